// Round 14
// baseline (411.475 us; speedup 1.0000x reference)
//
#include <hip/hip_runtime.h>

#define DH 64
#define DIN 32
#define BSH 8                 // bucket = dst >> 8 (256-node ranges)
#define BNODES 256
#define MAXB 1024
#define CAPSH 13              // per-bucket capacity 8192 (avg fill ~4.1k, sigma ~64)
#define CAP (1 << CAPSH)

typedef unsigned short u16;
typedef unsigned int u32;

__device__ __forceinline__ float bf2f(u16 u) {
    union { u32 i; float f; } x; x.i = ((u32)u) << 16; return x.f;
}
__device__ __forceinline__ u16 f2bf(float f) {
    union { float f; u32 i; } x; x.f = f;
    u32 r = x.i + 0x7fff + ((x.i >> 16) & 1);    // round-to-nearest-even
    return (u16)(r >> 16);
}

// bin packed (src<<BSH | local_dst) into fixed-capacity bucket spans with
// per-(block,bucket) private sub-spans. Grid-stride granules.
// Edge layout (int32 vs int64) detected inline by wave 0.
__global__ void __launch_bounds__(256) binA_k(
        const int* __restrict__ ei, int* __restrict__ gcnt,
        u32* __restrict__ pairs, int E, int n, int nbuck) {
    __shared__ int lhist[MAXB];
    __shared__ int lbase[MAXB];
    __shared__ int smode;
    int t = threadIdx.x;
    if (t < 64) {   // int64 layout: odd 32-bit words are zero high-words
        int v = (2 * t + 1 < 2 * E) ? ei[2 * t + 1] : 0;
        unsigned long long b = __ballot(v != 0);
        if (t == 0) smode = (b != 0ULL) ? 1 : 0;
    }
    for (int b = t; b < nbuck; b += 256) lhist[b] = 0;
    __syncthreads();
    int m = smode;
    unsigned un = (unsigned)n;
    int q0 = blockIdx.x * 256 + t;
    int qs = gridDim.x * 256;

    // ---- phase 1: count this block's edges per bucket
    if (m && !(E & 3)) {                       // int32, 4 edges per int4
        const int4* d4 = (const int4*)(ei + E);
        for (int q = q0; q < (E >> 2); q += qs) {
            int4 d = d4[q];
            if ((unsigned)d.x < un) atomicAdd(&lhist[d.x >> BSH], 1);
            if ((unsigned)d.y < un) atomicAdd(&lhist[d.y >> BSH], 1);
            if ((unsigned)d.z < un) atomicAdd(&lhist[d.z >> BSH], 1);
            if ((unsigned)d.w < un) atomicAdd(&lhist[d.w >> BSH], 1);
        }
    } else if (!m && !(E & 1)) {               // int64, 2 edges per int4
        const int4* d4 = (const int4*)(ei + 2 * E);
        for (int q = q0; q < (E >> 1); q += qs) {
            int4 d = d4[q];
            if ((unsigned)d.x < un) atomicAdd(&lhist[d.x >> BSH], 1);
            if ((unsigned)d.z < un) atomicAdd(&lhist[d.z >> BSH], 1);
        }
    } else {
        const int* dstp = m ? (ei + E) : (ei + 2 * E);
        int stride = m ? 1 : 2;
        for (int e = q0; e < E; e += qs) {
            int d = dstp[(size_t)e * stride];
            if ((unsigned)d < un) atomicAdd(&lhist[d >> BSH], 1);
        }
    }
    __syncthreads();
    // ---- phase 2: reserve private spans
    for (int b = t; b < nbuck; b += 256) {
        int c = lhist[b];
        lbase[b] = c ? ((b << CAPSH) + atomicAdd(&gcnt[b], c)) : 0;
        lhist[b] = 0;                          // reuse as local cursor
    }
    __syncthreads();
    // ---- phase 3: scatter into private spans
    #define EMIT(S, D)                                                     \
        if ((unsigned)(D) < un) {                                          \
            int sv = ((unsigned)(S) < un) ? (S) : 0;                       \
            int bb = (D) >> BSH;                                           \
            int off = atomicAdd(&lhist[bb], 1);                            \
            int pos = lbase[bb] + off;                                     \
            if (pos < ((bb + 1) << CAPSH))                                 \
                pairs[pos] = ((u32)sv << BSH) | (u32)((D) & (BNODES - 1)); \
        }
    if (m && !(E & 3)) {
        const int4* s4 = (const int4*)ei;
        const int4* d4 = (const int4*)(ei + E);
        for (int q = q0; q < (E >> 2); q += qs) {
            int4 s = s4[q]; int4 d = d4[q];
            EMIT(s.x, d.x) EMIT(s.y, d.y) EMIT(s.z, d.z) EMIT(s.w, d.w)
        }
    } else if (!m && !(E & 1)) {
        const int4* s4 = (const int4*)ei;
        const int4* d4 = (const int4*)(ei + 2 * E);
        for (int q = q0; q < (E >> 1); q += qs) {
            int4 s = s4[q]; int4 d = d4[q];
            EMIT(s.x, d.x) EMIT(s.z, d.z)
        }
    } else {
        const int* srcp = ei;
        const int* dstp = m ? (ei + E) : (ei + 2 * E);
        int stride = m ? 1 : 2;
        for (int e = q0; e < E; e += qs) {
            int d = dstp[(size_t)e * stride];
            int s = srcp[(size_t)e * stride];
            EMIT(s, d)
        }
    }
    #undef EMIT
}

// one block (512 thr) per bucket: CSR build FUSED with gemm1.
// Bucket b's pairs span is EXACTLY its 256 nodes' hp rows; phases A/B consume
// pairs, phase C overwrites the span in place with h1' bf16.
__global__ void __launch_bounds__(512) csr_gemm_k(
        u32* __restrict__ pairs, const int* __restrict__ gcnt,
        int* __restrict__ rstart, int* __restrict__ rend,
        int* __restrict__ col, float* __restrict__ dinv,
        const float* __restrict__ x, const float* __restrict__ W1, int N) {
    __shared__ int cnt[BNODES];
    __shared__ int s[BNODES];
    __shared__ float dl[BNODES];
    __shared__ float Wl[DIN * DH];           // 8 KB
    __shared__ float xl[32][DIN + 4];        // 4.6 KB
    int b = blockIdx.x, t = threadIdx.x;
    int base = b << CAPSH;
    int ec = gcnt[b]; if (ec > CAP) ec = CAP;
    int end = base + ec;
    ((float4*)Wl)[t] = ((const float4*)W1)[t];
    if (t < BNODES) cnt[t] = 0;
    __syncthreads();
    for (int i = base + t; i < end; i += 512)
        atomicAdd(&cnt[pairs[i] & (BNODES - 1)], 1);
    __syncthreads();
    int v = (t < BNODES) ? cnt[t] : 0;
    if (t < BNODES) s[t] = v;
    __syncthreads();
    for (int off = 1; off < BNODES; off <<= 1) {
        int xsc = (t >= off && t < BNODES) ? s[t - off] : 0;
        __syncthreads();
        if (t < BNODES) s[t] += xsc;
        __syncthreads();
    }
    if (t < BNODES) {
        int excl = s[t] - v;
        int a = base + excl;
        int node = (b << BSH) + t;
        float di = rsqrtf((float)v + 1.0f);
        dl[t] = di;
        if (node < N) {
            rstart[node] = a;
            rend[node]   = a + v;
            dinv[node]   = di;
        }
        cnt[t] = a;                            // cursor
    }
    __syncthreads();
    for (int i = base + t; i < end; i += 512) {
        u32 p = pairs[i];
        int pos = atomicAdd(&cnt[p & (BNODES - 1)], 1);
        col[pos] = (int)(p >> BSH);
    }
    __syncthreads();                           // pairs fully consumed
    u16* hp = (u16*)pairs;                     // device-global base; rows by node id
    int lane = t & 63, w = t >> 6;             // 8 waves
    int g = lane >> 4, c = lane & 15;
    for (int it = 0; it < 8; it++) {
        int nl0 = it * 32;
        __syncthreads();
        if (t < 256) {
            int idx = t * 4;
            int row = idx / DIN, ck = idx % DIN;
            int node = (b << BSH) + nl0 + row;
            float4 vx = {0.f, 0.f, 0.f, 0.f};
            if (node < N)
                vx = *(const float4*)&x[(size_t)node * DIN + ck];
            *(float4*)&xl[row][ck] = vx;
        }
        __syncthreads();
        int nl = nl0 + w * 4 + g;
        int node = (b << BSH) + nl;
        const float* xr = xl[nl - nl0];
        float4 acc = {0.f, 0.f, 0.f, 0.f};
        #pragma unroll
        for (int k = 0; k < DIN; k++) {
            float xv = xr[k];
            float4 wv = *(const float4*)&Wl[k * DH + c * 4];
            acc.x += xv * wv.x; acc.y += xv * wv.y; acc.z += xv * wv.z; acc.w += xv * wv.w;
        }
        if (node < N) {
            float di = dl[nl];
            ushort4 o;
            o.x = f2bf(acc.x * di); o.y = f2bf(acc.y * di);
            o.z = f2bf(acc.z * di); o.w = f2bf(acc.w * di);
            *(ushort4*)&hp[(size_t)node * DH + c * 4] = o;
        }
    }
}

// two-node interleaved edge sum: 16-lane group g owns nodes n0 and n1; two
// independent col-load->gather chains (cb0/cb1) interleaved 4+4 per step so
// the second chain issues while the first drains. Loop bound is wave-uniform
// degmax so every __shfl executes with all lanes active.
__device__ __forceinline__ void edge_sum2(const u16* __restrict__ hp,
                                          const int* __restrict__ col,
                                          int s0, int d0, int s1, int d1,
                                          int g, int c,
                                          float4& A0, float4& A1) {
    int dm = max(d0, d1);
    dm = max(dm, __shfl_xor(dm, 16, 64));
    dm = max(dm, __shfl_xor(dm, 32, 64));
    float4 acc0 = {0.f, 0.f, 0.f, 0.f};
    float4 acc1 = {0.f, 0.f, 0.f, 0.f};
    if (dm > 0) {
        int gl = g << 4;
        int cb0 = (c < d0) ? col[s0 + c] : 0;
        int cb1 = (c < d1) ? col[s1 + c] : 0;
        for (int base = 0; base < dm; base += 16) {
            int nb = base + 16;
            int cbn0 = 0, cbn1 = 0;
            if (nb < dm) {
                cbn0 = (nb + c < d0) ? col[s0 + nb + c] : 0;
                cbn1 = (nb + c < d1) ? col[s1 + nb + c] : 0;
            }
            int rm = dm - base; if (rm > 16) rm = 16;
            for (int j = 0; j < rm; j += 4) {
                int t0 = __shfl(cb0, gl | j, 64);
                int t1 = __shfl(cb0, gl | (j + 1), 64);
                int t2 = __shfl(cb0, gl | (j + 2), 64);
                int t3 = __shfl(cb0, gl | (j + 3), 64);
                int u0 = __shfl(cb1, gl | j, 64);
                int u1 = __shfl(cb1, gl | (j + 1), 64);
                int u2 = __shfl(cb1, gl | (j + 2), 64);
                int u3 = __shfl(cb1, gl | (j + 3), 64);
                bool p0 = base + j     < d0;
                bool p1 = base + j + 1 < d0;
                bool p2 = base + j + 2 < d0;
                bool p3 = base + j + 3 < d0;
                bool q0 = base + j     < d1;
                bool q1 = base + j + 1 < d1;
                bool q2 = base + j + 2 < d1;
                bool q3 = base + j + 3 < d1;
                ushort4 v0, v1, v2, v3, w0, w1, w2, w3;
                if (p0) v0 = *(const ushort4*)&hp[(size_t)t0 * DH + c * 4];
                if (q0) w0 = *(const ushort4*)&hp[(size_t)u0 * DH + c * 4];
                if (p1) v1 = *(const ushort4*)&hp[(size_t)t1 * DH + c * 4];
                if (q1) w1 = *(const ushort4*)&hp[(size_t)u1 * DH + c * 4];
                if (p2) v2 = *(const ushort4*)&hp[(size_t)t2 * DH + c * 4];
                if (q2) w2 = *(const ushort4*)&hp[(size_t)u2 * DH + c * 4];
                if (p3) v3 = *(const ushort4*)&hp[(size_t)t3 * DH + c * 4];
                if (q3) w3 = *(const ushort4*)&hp[(size_t)u3 * DH + c * 4];
                if (p0) { acc0.x += bf2f(v0.x); acc0.y += bf2f(v0.y); acc0.z += bf2f(v0.z); acc0.w += bf2f(v0.w); }
                if (q0) { acc1.x += bf2f(w0.x); acc1.y += bf2f(w0.y); acc1.z += bf2f(w0.z); acc1.w += bf2f(w0.w); }
                if (p1) { acc0.x += bf2f(v1.x); acc0.y += bf2f(v1.y); acc0.z += bf2f(v1.z); acc0.w += bf2f(v1.w); }
                if (q1) { acc1.x += bf2f(w1.x); acc1.y += bf2f(w1.y); acc1.z += bf2f(w1.z); acc1.w += bf2f(w1.w); }
                if (p2) { acc0.x += bf2f(v2.x); acc0.y += bf2f(v2.y); acc0.z += bf2f(v2.z); acc0.w += bf2f(v2.w); }
                if (q2) { acc1.x += bf2f(w2.x); acc1.y += bf2f(w2.y); acc1.z += bf2f(w2.z); acc1.w += bf2f(w2.w); }
                if (p3) { acc0.x += bf2f(v3.x); acc0.y += bf2f(v3.y); acc0.z += bf2f(v3.z); acc0.w += bf2f(v3.w); }
                if (q3) { acc1.x += bf2f(w3.x); acc1.y += bf2f(w3.y); acc1.z += bf2f(w3.z); acc1.w += bf2f(w3.w); }
            }
            cb0 = cbn0; cb1 = cbn1;
        }
    }
    A0 = acc0; A1 = acc1;
}

// FUSED layer-1 aggregation + layer-2 GEMM, 2 nodes/group (wave = 8 nodes):
// out1 = (h1'[d] + sum_neighbors)*dinv + b1 ; h2' = (relu(out1) @ W2)*dinv -> bf16
__global__ void __launch_bounds__(256) agg_gemm_k(
        const u16* __restrict__ hp, const int* __restrict__ rstart,
        const int* __restrict__ rend, const int* __restrict__ col,
        const float* __restrict__ dinv, const float* __restrict__ b1,
        const float* __restrict__ W2, u16* __restrict__ hp2, int N) {
    __shared__ float Wl[DH * DH];            // 16 KB
    __shared__ float xs[4][8][DH + 4];       // 8 rows/wave, 68-float stride (8.5 KB)
    int tid = threadIdx.x;
    {
        const float4* Wv = (const float4*)W2;
        float4* Wd = (float4*)Wl;
        #pragma unroll
        for (int r = 0; r < 4; r++) Wd[tid + 256 * r] = Wv[tid + 256 * r];
    }
    __syncthreads();
    int lane = tid & 63, w = tid >> 6;
    int g = lane >> 4, c = lane & 15;
    int n0 = blockIdx.x * 32 + w * 8 + g;
    int n1 = n0 + 4;
    int s0 = 0, d0 = 0, s1 = 0, d1 = 0;
    if (n0 < N) { s0 = rstart[n0]; d0 = rend[n0] - s0; }
    if (n1 < N) { s1 = rstart[n1]; d1 = rend[n1] - s1; }
    float4 a0, a1;
    edge_sum2(hp, col, s0, d0, s1, d1, g, c, a0, a1);
    float di0 = (n0 < N) ? dinv[n0] : 0.f;
    float di1 = (n1 < N) ? dinv[n1] : 0.f;
    float4 b = *(const float4*)&b1[c * 4];
    float4 o0 = {0.f, 0.f, 0.f, 0.f}, o1 = {0.f, 0.f, 0.f, 0.f};
    if (n0 < N) {
        ushort4 sv = *(const ushort4*)&hp[(size_t)n0 * DH + c * 4];
        o0.x = fmaxf((a0.x + bf2f(sv.x)) * di0 + b.x, 0.f);
        o0.y = fmaxf((a0.y + bf2f(sv.y)) * di0 + b.y, 0.f);
        o0.z = fmaxf((a0.z + bf2f(sv.z)) * di0 + b.z, 0.f);
        o0.w = fmaxf((a0.w + bf2f(sv.w)) * di0 + b.w, 0.f);
    }
    if (n1 < N) {
        ushort4 sv = *(const ushort4*)&hp[(size_t)n1 * DH + c * 4];
        o1.x = fmaxf((a1.x + bf2f(sv.x)) * di1 + b.x, 0.f);
        o1.y = fmaxf((a1.y + bf2f(sv.y)) * di1 + b.y, 0.f);
        o1.z = fmaxf((a1.z + bf2f(sv.z)) * di1 + b.z, 0.f);
        o1.w = fmaxf((a1.w + bf2f(sv.w)) * di1 + b.w, 0.f);
    }
    *(float4*)&xs[w][g][c * 4]     = o0;     // same-wave produce/consume, no barrier
    *(float4*)&xs[w][g + 4][c * 4] = o1;
    const float* xr0 = xs[w][g];
    const float* xr1 = xs[w][g + 4];
    float4 r0 = {0.f, 0.f, 0.f, 0.f}, r1 = {0.f, 0.f, 0.f, 0.f};
    #pragma unroll
    for (int k = 0; k < DH; k++) {
        float4 wv = *(const float4*)&Wl[k * DH + c * 4];
        float x0 = xr0[k], x1 = xr1[k];
        r0.x += x0 * wv.x; r0.y += x0 * wv.y; r0.z += x0 * wv.z; r0.w += x0 * wv.w;
        r1.x += x1 * wv.x; r1.y += x1 * wv.y; r1.z += x1 * wv.z; r1.w += x1 * wv.w;
    }
    if (n0 < N) {
        ushort4 po;
        po.x = f2bf(r0.x * di0); po.y = f2bf(r0.y * di0);
        po.z = f2bf(r0.z * di0); po.w = f2bf(r0.w * di0);
        *(ushort4*)&hp2[(size_t)n0 * DH + c * 4] = po;
    }
    if (n1 < N) {
        ushort4 po;
        po.x = f2bf(r1.x * di1); po.y = f2bf(r1.y * di1);
        po.z = f2bf(r1.z * di1); po.w = f2bf(r1.w * di1);
        *(ushort4*)&hp2[(size_t)n1 * DH + c * 4] = po;
    }
}

// fused layer-2 aggregation + head, 2 nodes/group: y = sigmoid(relu(out2).Wo+bo)
__global__ void __launch_bounds__(256) agg_head_k(
        const u16* __restrict__ hp, const int* __restrict__ rstart,
        const int* __restrict__ rend, const int* __restrict__ col,
        const float* __restrict__ dinv, const float* __restrict__ bias,
        const float* __restrict__ Wo, const float* __restrict__ bo,
        float* __restrict__ y, int N) {
    int lane = threadIdx.x & 63;
    int g = lane >> 4, c = lane & 15;
    int n0 = blockIdx.x * 32 + (threadIdx.x >> 6) * 8 + g;
    int n1 = n0 + 4;
    int s0 = 0, d0 = 0, s1 = 0, d1 = 0;
    if (n0 < N) { s0 = rstart[n0]; d0 = rend[n0] - s0; }
    if (n1 < N) { s1 = rstart[n1]; d1 = rend[n1] - s1; }
    float4 a0, a1;
    edge_sum2(hp, col, s0, d0, s1, d1, g, c, a0, a1);
    float4 b = *(const float4*)&bias[c * 4];
    float4 wo = *(const float4*)&Wo[c * 4];
    float t0 = 0.f, t1 = 0.f;
    if (n0 < N) {
        ushort4 sv = *(const ushort4*)&hp[(size_t)n0 * DH + c * 4];
        float di = dinv[n0];
        t0 = fmaxf((a0.x + bf2f(sv.x)) * di + b.x, 0.f) * wo.x
           + fmaxf((a0.y + bf2f(sv.y)) * di + b.y, 0.f) * wo.y
           + fmaxf((a0.z + bf2f(sv.z)) * di + b.z, 0.f) * wo.z
           + fmaxf((a0.w + bf2f(sv.w)) * di + b.w, 0.f) * wo.w;
    }
    if (n1 < N) {
        ushort4 sv = *(const ushort4*)&hp[(size_t)n1 * DH + c * 4];
        float di = dinv[n1];
        t1 = fmaxf((a1.x + bf2f(sv.x)) * di + b.x, 0.f) * wo.x
           + fmaxf((a1.y + bf2f(sv.y)) * di + b.y, 0.f) * wo.y
           + fmaxf((a1.z + bf2f(sv.z)) * di + b.z, 0.f) * wo.z
           + fmaxf((a1.w + bf2f(sv.w)) * di + b.w, 0.f) * wo.w;
    }
    #pragma unroll
    for (int m = 1; m < 16; m <<= 1) {
        t0 += __shfl_xor(t0, m, 64);
        t1 += __shfl_xor(t1, m, 64);
    }
    if (c == 0) {
        if (n0 < N) y[n0] = 1.f / (1.f + __expf(-(t0 + bo[0])));
        if (n1 < N) y[n1] = 1.f / (1.f + __expf(-(t1 + bo[0])));
    }
}

extern "C" void kernel_launch(void* const* d_in, const int* in_sizes, int n_in,
                              void* d_out, int out_size, void* d_ws, size_t ws_size,
                              hipStream_t stream) {
    const float* x  = (const float*)d_in[0];
    const int*   ei = (const int*)d_in[1];
    const float* W1 = (const float*)d_in[2];
    const float* b1 = (const float*)d_in[3];
    const float* W2 = (const float*)d_in[4];
    const float* b2 = (const float*)d_in[5];
    const float* Wo = (const float*)d_in[6];
    const float* bo = (const float*)d_in[7];
    float* y = (float*)d_out;

    int N = in_sizes[0] / DIN;
    int E = in_sizes[1] / 2;
    int nbuck = ((N - 1) >> BSH) + 1;            // 391 for N=100k (<= MAXB)

    char* ws = (char*)d_ws;
    size_t off = 0;
    auto alloc = [&](size_t bytes) { char* p = ws + off; off += (bytes + 255) & ~(size_t)255; return p; };
    int*   gcnt   = (int*)alloc(MAXB * 4);
    int*   rstart = (int*)alloc((size_t)N * 4);
    int*   rend   = (int*)alloc((size_t)N * 4);
    float* dinv   = (float*)alloc((size_t)N * 4);
    int*   col    = (int*)alloc(((size_t)nbuck << CAPSH) * 4);   // ~12.8 MB
    size_t pair_b = ((size_t)nbuck << CAPSH) * 4;
    size_t hp_b   = (size_t)N * DH * 2;
    char*  bufA   = (char*)alloc(pair_b > hp_b ? pair_b : hp_b); // pairs / h1' alias (same spans!)
    u16*   bufB   = (u16*)alloc(hp_b);                           // h2' bf16
    u16*   hp    = (u16*)bufA;
    u32*   pairs = (u32*)bufA;

    int gN32 = (N + 31) / 32;

    hipMemsetAsync(gcnt, 0, (size_t)nbuck * 4, stream);
    binA_k<<<768, 256, 0, stream>>>(ei, gcnt, pairs, E, N, nbuck);
    // CSR build + layer-1 transform fused (pairs consumed, hp written in place)
    csr_gemm_k<<<nbuck, 512, 0, stream>>>(pairs, gcnt, rstart, rend, col, dinv, x, W1, N);
    // layer-1 aggregation fused with layer-2 transform: bufB = h2'
    agg_gemm_k<<<gN32, 256, 0, stream>>>(hp, rstart, rend, col, dinv, b1, W2, bufB, N);
    // layer-2 aggregation fused with head
    agg_head_k<<<gN32, 256, 0, stream>>>(bufB, rstart, rend, col, dinv, b2, Wo, bo, y, N);
}

// Round 15
// 197.598 us; speedup vs baseline: 2.0824x; 2.0824x over previous
//
#include <hip/hip_runtime.h>

#define DH 64
#define DIN 32
#define BSH 8                 // bucket = dst >> 8 (256-node ranges)
#define BNODES 256
#define MAXB 1024
#define CAPSH 13              // per-bucket capacity 8192 (avg fill ~4.1k, sigma ~64)
#define CAP (1 << CAPSH)

typedef unsigned short u16;
typedef unsigned int u32;

__device__ __forceinline__ float bf2f(u16 u) {
    union { u32 i; float f; } x; x.i = ((u32)u) << 16; return x.f;
}
__device__ __forceinline__ u16 f2bf(float f) {
    union { float f; u32 i; } x; x.f = f;
    u32 r = x.i + 0x7fff + ((x.i >> 16) & 1);    // round-to-nearest-even
    return (u16)(r >> 16);
}

// bin packed (src<<BSH | local_dst) into fixed-capacity bucket spans with
// per-(block,bucket) private sub-spans. Grid-stride granules.
// Edge layout (int32 vs int64) detected inline by wave 0.
__global__ void __launch_bounds__(256) binA_k(
        const int* __restrict__ ei, int* __restrict__ gcnt,
        u32* __restrict__ pairs, int E, int n, int nbuck) {
    __shared__ int lhist[MAXB];
    __shared__ int lbase[MAXB];
    __shared__ int smode;
    int t = threadIdx.x;
    if (t < 64) {   // int64 layout: odd 32-bit words are zero high-words
        int v = (2 * t + 1 < 2 * E) ? ei[2 * t + 1] : 0;
        unsigned long long b = __ballot(v != 0);
        if (t == 0) smode = (b != 0ULL) ? 1 : 0;
    }
    for (int b = t; b < nbuck; b += 256) lhist[b] = 0;
    __syncthreads();
    int m = smode;
    unsigned un = (unsigned)n;
    int q0 = blockIdx.x * 256 + t;
    int qs = gridDim.x * 256;

    // ---- phase 1: count this block's edges per bucket
    if (m && !(E & 3)) {                       // int32, 4 edges per int4
        const int4* d4 = (const int4*)(ei + E);
        for (int q = q0; q < (E >> 2); q += qs) {
            int4 d = d4[q];
            if ((unsigned)d.x < un) atomicAdd(&lhist[d.x >> BSH], 1);
            if ((unsigned)d.y < un) atomicAdd(&lhist[d.y >> BSH], 1);
            if ((unsigned)d.z < un) atomicAdd(&lhist[d.z >> BSH], 1);
            if ((unsigned)d.w < un) atomicAdd(&lhist[d.w >> BSH], 1);
        }
    } else if (!m && !(E & 1)) {               // int64, 2 edges per int4
        const int4* d4 = (const int4*)(ei + 2 * E);
        for (int q = q0; q < (E >> 1); q += qs) {
            int4 d = d4[q];
            if ((unsigned)d.x < un) atomicAdd(&lhist[d.x >> BSH], 1);
            if ((unsigned)d.z < un) atomicAdd(&lhist[d.z >> BSH], 1);
        }
    } else {
        const int* dstp = m ? (ei + E) : (ei + 2 * E);
        int stride = m ? 1 : 2;
        for (int e = q0; e < E; e += qs) {
            int d = dstp[(size_t)e * stride];
            if ((unsigned)d < un) atomicAdd(&lhist[d >> BSH], 1);
        }
    }
    __syncthreads();
    // ---- phase 2: reserve private spans
    for (int b = t; b < nbuck; b += 256) {
        int c = lhist[b];
        lbase[b] = c ? ((b << CAPSH) + atomicAdd(&gcnt[b], c)) : 0;
        lhist[b] = 0;                          // reuse as local cursor
    }
    __syncthreads();
    // ---- phase 3: scatter into private spans
    #define EMIT(S, D)                                                     \
        if ((unsigned)(D) < un) {                                          \
            int sv = ((unsigned)(S) < un) ? (S) : 0;                       \
            int bb = (D) >> BSH;                                           \
            int off = atomicAdd(&lhist[bb], 1);                            \
            int pos = lbase[bb] + off;                                     \
            if (pos < ((bb + 1) << CAPSH))                                 \
                pairs[pos] = ((u32)sv << BSH) | (u32)((D) & (BNODES - 1)); \
        }
    if (m && !(E & 3)) {
        const int4* s4 = (const int4*)ei;
        const int4* d4 = (const int4*)(ei + E);
        for (int q = q0; q < (E >> 2); q += qs) {
            int4 s = s4[q]; int4 d = d4[q];
            EMIT(s.x, d.x) EMIT(s.y, d.y) EMIT(s.z, d.z) EMIT(s.w, d.w)
        }
    } else if (!m && !(E & 1)) {
        const int4* s4 = (const int4*)ei;
        const int4* d4 = (const int4*)(ei + 2 * E);
        for (int q = q0; q < (E >> 1); q += qs) {
            int4 s = s4[q]; int4 d = d4[q];
            EMIT(s.x, d.x) EMIT(s.z, d.z)
        }
    } else {
        const int* srcp = ei;
        const int* dstp = m ? (ei + E) : (ei + 2 * E);
        int stride = m ? 1 : 2;
        for (int e = q0; e < E; e += qs) {
            int d = dstp[(size_t)e * stride];
            int s = srcp[(size_t)e * stride];
            EMIT(s, d)
        }
    }
    #undef EMIT
}

// one block (512 thr) per bucket: CSR build FUSED with gemm1.
// Bucket b's pairs span is EXACTLY its 256 nodes' hp rows; phases A/B consume
// pairs, phase C overwrites the span in place with h1' bf16.
__global__ void __launch_bounds__(512) csr_gemm_k(
        u32* __restrict__ pairs, const int* __restrict__ gcnt,
        int* __restrict__ rstart, int* __restrict__ rend,
        int* __restrict__ col, float* __restrict__ dinv,
        const float* __restrict__ x, const float* __restrict__ W1, int N) {
    __shared__ int cnt[BNODES];
    __shared__ int s[BNODES];
    __shared__ float dl[BNODES];
    __shared__ float Wl[DIN * DH];           // 8 KB
    __shared__ float xl[32][DIN + 4];        // 4.6 KB
    int b = blockIdx.x, t = threadIdx.x;
    int base = b << CAPSH;
    int ec = gcnt[b]; if (ec > CAP) ec = CAP;
    int end = base + ec;
    ((float4*)Wl)[t] = ((const float4*)W1)[t];
    if (t < BNODES) cnt[t] = 0;
    __syncthreads();
    for (int i = base + t; i < end; i += 512)
        atomicAdd(&cnt[pairs[i] & (BNODES - 1)], 1);
    __syncthreads();
    int v = (t < BNODES) ? cnt[t] : 0;
    if (t < BNODES) s[t] = v;
    __syncthreads();
    for (int off = 1; off < BNODES; off <<= 1) {
        int xsc = (t >= off && t < BNODES) ? s[t - off] : 0;
        __syncthreads();
        if (t < BNODES) s[t] += xsc;
        __syncthreads();
    }
    if (t < BNODES) {
        int excl = s[t] - v;
        int a = base + excl;
        int node = (b << BSH) + t;
        float di = rsqrtf((float)v + 1.0f);
        dl[t] = di;
        if (node < N) {
            rstart[node] = a;
            rend[node]   = a + v;
            dinv[node]   = di;
        }
        cnt[t] = a;                            // cursor
    }
    __syncthreads();
    for (int i = base + t; i < end; i += 512) {
        u32 p = pairs[i];
        int pos = atomicAdd(&cnt[p & (BNODES - 1)], 1);
        col[pos] = (int)(p >> BSH);
    }
    __syncthreads();                           // pairs fully consumed
    u16* hp = (u16*)pairs;                     // device-global base; rows by node id
    int lane = t & 63, w = t >> 6;             // 8 waves
    int g = lane >> 4, c = lane & 15;
    for (int it = 0; it < 8; it++) {
        int nl0 = it * 32;
        __syncthreads();
        if (t < 256) {
            int idx = t * 4;
            int row = idx / DIN, ck = idx % DIN;
            int node = (b << BSH) + nl0 + row;
            float4 vx = {0.f, 0.f, 0.f, 0.f};
            if (node < N)
                vx = *(const float4*)&x[(size_t)node * DIN + ck];
            *(float4*)&xl[row][ck] = vx;
        }
        __syncthreads();
        int nl = nl0 + w * 4 + g;
        int node = (b << BSH) + nl;
        const float* xr = xl[nl - nl0];
        float4 acc = {0.f, 0.f, 0.f, 0.f};
        #pragma unroll
        for (int k = 0; k < DIN; k++) {
            float xv = xr[k];
            float4 wv = *(const float4*)&Wl[k * DH + c * 4];
            acc.x += xv * wv.x; acc.y += xv * wv.y; acc.z += xv * wv.z; acc.w += xv * wv.w;
        }
        if (node < N) {
            float di = dl[nl];
            ushort4 o;
            o.x = f2bf(acc.x * di); o.y = f2bf(acc.y * di);
            o.z = f2bf(acc.z * di); o.w = f2bf(acc.w * di);
            *(ushort4*)&hp[(size_t)node * DH + c * 4] = o;
        }
    }
}

// group-per-node edge sum: 16-lane group g owns node; c=lane&15 (4 cols, 8B).
// 8-deep gather pipeline + next-chunk col prefetch; loop bound is wave-uniform
// degmax so every __shfl executes with all lanes active.
__device__ __forceinline__ float4 edge_sum_grp(const u16* __restrict__ hp,
                                               const int* __restrict__ col,
                                               int start, int deg, int g, int c) {
    int dm = deg;
    dm = max(dm, __shfl_xor(dm, 16, 64));
    dm = max(dm, __shfl_xor(dm, 32, 64));
    float4 acc = {0.f, 0.f, 0.f, 0.f};
    if (dm <= 0) return acc;
    int gl = g << 4;
    int cb = (c < deg) ? col[start + c] : 0;   // chunk 0 col slice
    for (int base = 0; base < dm; base += 16) {
        int nb = base + 16;
        int cbn = 0;
        if (nb < dm) cbn = (nb + c < deg) ? col[start + nb + c] : 0;  // prefetch next chunk
        int rm = dm - base; if (rm > 16) rm = 16;
        for (int j = 0; j < rm; j += 8) {
            int s0 = __shfl(cb, gl | j, 64);
            int s1 = __shfl(cb, gl | (j + 1), 64);
            int s2 = __shfl(cb, gl | (j + 2), 64);
            int s3 = __shfl(cb, gl | (j + 3), 64);
            int s4 = __shfl(cb, gl | (j + 4), 64);
            int s5 = __shfl(cb, gl | (j + 5), 64);
            int s6 = __shfl(cb, gl | (j + 6), 64);
            int s7 = __shfl(cb, gl | (j + 7), 64);
            bool a0 = base + j     < deg;
            bool a1 = base + j + 1 < deg;
            bool a2 = base + j + 2 < deg;
            bool a3 = base + j + 3 < deg;
            bool a4 = base + j + 4 < deg;
            bool a5 = base + j + 5 < deg;
            bool a6 = base + j + 6 < deg;
            bool a7 = base + j + 7 < deg;
            ushort4 v0, v1, v2, v3, v4, v5, v6, v7;
            if (a0) v0 = *(const ushort4*)&hp[(size_t)s0 * DH + c * 4];
            if (a1) v1 = *(const ushort4*)&hp[(size_t)s1 * DH + c * 4];
            if (a2) v2 = *(const ushort4*)&hp[(size_t)s2 * DH + c * 4];
            if (a3) v3 = *(const ushort4*)&hp[(size_t)s3 * DH + c * 4];
            if (a4) v4 = *(const ushort4*)&hp[(size_t)s4 * DH + c * 4];
            if (a5) v5 = *(const ushort4*)&hp[(size_t)s5 * DH + c * 4];
            if (a6) v6 = *(const ushort4*)&hp[(size_t)s6 * DH + c * 4];
            if (a7) v7 = *(const ushort4*)&hp[(size_t)s7 * DH + c * 4];
            if (a0) { acc.x += bf2f(v0.x); acc.y += bf2f(v0.y); acc.z += bf2f(v0.z); acc.w += bf2f(v0.w); }
            if (a1) { acc.x += bf2f(v1.x); acc.y += bf2f(v1.y); acc.z += bf2f(v1.z); acc.w += bf2f(v1.w); }
            if (a2) { acc.x += bf2f(v2.x); acc.y += bf2f(v2.y); acc.z += bf2f(v2.z); acc.w += bf2f(v2.w); }
            if (a3) { acc.x += bf2f(v3.x); acc.y += bf2f(v3.y); acc.z += bf2f(v3.z); acc.w += bf2f(v3.w); }
            if (a4) { acc.x += bf2f(v4.x); acc.y += bf2f(v4.y); acc.z += bf2f(v4.z); acc.w += bf2f(v4.w); }
            if (a5) { acc.x += bf2f(v5.x); acc.y += bf2f(v5.y); acc.z += bf2f(v5.z); acc.w += bf2f(v5.w); }
            if (a6) { acc.x += bf2f(v6.x); acc.y += bf2f(v6.y); acc.z += bf2f(v6.z); acc.w += bf2f(v6.w); }
            if (a7) { acc.x += bf2f(v7.x); acc.y += bf2f(v7.y); acc.z += bf2f(v7.z); acc.w += bf2f(v7.w); }
        }
        cb = cbn;
    }
    return acc;
}

// FUSED layer-1 aggregation + layer-2 GEMM:
// out1 = (h1'[d] + sum_neighbors)*dinv + b1 ; h2' = (relu(out1) @ W2) * dinv -> bf16
__global__ void __launch_bounds__(256) agg_gemm_k(
        const u16* __restrict__ hp, const int* __restrict__ rstart,
        const int* __restrict__ rend, const int* __restrict__ col,
        const float* __restrict__ dinv, const float* __restrict__ b1,
        const float* __restrict__ W2, u16* __restrict__ hp2, int N) {
    __shared__ float Wl[DH * DH];            // 16 KB
    __shared__ float xs[4][4][DH + 4];       // wave-private rows, 68-float stride
    int tid = threadIdx.x;
    {
        const float4* Wv = (const float4*)W2;
        float4* Wd = (float4*)Wl;
        #pragma unroll
        for (int r = 0; r < 4; r++) Wd[tid + 256 * r] = Wv[tid + 256 * r];
    }
    __syncthreads();
    int lane = tid & 63, w = tid >> 6;
    int g = lane >> 4, c = lane & 15;
    int node = blockIdx.x * 16 + w * 4 + g;
    int start = 0, deg = 0;
    if (node < N) { start = rstart[node]; deg = rend[node] - start; }
    float4 acc = edge_sum_grp(hp, col, start, deg, g, c);
    float di = (node < N) ? dinv[node] : 0.f;
    float4 o = {0.f, 0.f, 0.f, 0.f};
    if (node < N) {
        ushort4 sv = *(const ushort4*)&hp[(size_t)node * DH + c * 4];
        float4 b = *(const float4*)&b1[c * 4];
        o.x = fmaxf((acc.x + bf2f(sv.x)) * di + b.x, 0.f);
        o.y = fmaxf((acc.y + bf2f(sv.y)) * di + b.y, 0.f);
        o.z = fmaxf((acc.z + bf2f(sv.z)) * di + b.z, 0.f);
        o.w = fmaxf((acc.w + bf2f(sv.w)) * di + b.w, 0.f);
    }
    *(float4*)&xs[w][g][c * 4] = o;          // same-wave produce/consume, no barrier
    const float* xr = xs[w][g];
    float4 a2 = {0.f, 0.f, 0.f, 0.f};
    #pragma unroll
    for (int k = 0; k < DH; k++) {
        float xv = xr[k];
        float4 wv = *(const float4*)&Wl[k * DH + c * 4];
        a2.x += xv * wv.x; a2.y += xv * wv.y; a2.z += xv * wv.z; a2.w += xv * wv.w;
    }
    if (node < N) {
        ushort4 po;
        po.x = f2bf(a2.x * di); po.y = f2bf(a2.y * di);
        po.z = f2bf(a2.z * di); po.w = f2bf(a2.w * di);
        *(ushort4*)&hp2[(size_t)node * DH + c * 4] = po;
    }
}

// fused layer-2 aggregation + head: y = sigmoid(relu(out2) . Wo + bo)
__global__ void __launch_bounds__(256) agg_head_k(
        const u16* __restrict__ hp, const int* __restrict__ rstart,
        const int* __restrict__ rend, const int* __restrict__ col,
        const float* __restrict__ dinv, const float* __restrict__ bias,
        const float* __restrict__ Wo, const float* __restrict__ bo,
        float* __restrict__ y, int N) {
    int lane = threadIdx.x & 63;
    int g = lane >> 4, c = lane & 15;
    int node = blockIdx.x * 16 + (threadIdx.x >> 6) * 4 + g;
    int start = 0, deg = 0;
    if (node < N) { start = rstart[node]; deg = rend[node] - start; }
    float4 acc = edge_sum_grp(hp, col, start, deg, g, c);
    float t = 0.f;
    if (node < N) {
        ushort4 sv = *(const ushort4*)&hp[(size_t)node * DH + c * 4];
        float4 b = *(const float4*)&bias[c * 4];
        float4 wo = *(const float4*)&Wo[c * 4];
        float di = dinv[node];
        t = fmaxf((acc.x + bf2f(sv.x)) * di + b.x, 0.f) * wo.x
          + fmaxf((acc.y + bf2f(sv.y)) * di + b.y, 0.f) * wo.y
          + fmaxf((acc.z + bf2f(sv.z)) * di + b.z, 0.f) * wo.z
          + fmaxf((acc.w + bf2f(sv.w)) * di + b.w, 0.f) * wo.w;
    }
    #pragma unroll
    for (int m = 1; m < 16; m <<= 1) t += __shfl_xor(t, m, 64);
    if (c == 0 && node < N) {
        float z = t + bo[0];
        y[node] = 1.f / (1.f + __expf(-z));
    }
}

extern "C" void kernel_launch(void* const* d_in, const int* in_sizes, int n_in,
                              void* d_out, int out_size, void* d_ws, size_t ws_size,
                              hipStream_t stream) {
    const float* x  = (const float*)d_in[0];
    const int*   ei = (const int*)d_in[1];
    const float* W1 = (const float*)d_in[2];
    const float* b1 = (const float*)d_in[3];
    const float* W2 = (const float*)d_in[4];
    const float* b2 = (const float*)d_in[5];
    const float* Wo = (const float*)d_in[6];
    const float* bo = (const float*)d_in[7];
    float* y = (float*)d_out;

    int N = in_sizes[0] / DIN;
    int E = in_sizes[1] / 2;
    int nbuck = ((N - 1) >> BSH) + 1;            // 391 for N=100k (<= MAXB)

    char* ws = (char*)d_ws;
    size_t off = 0;
    auto alloc = [&](size_t bytes) { char* p = ws + off; off += (bytes + 255) & ~(size_t)255; return p; };
    int*   gcnt   = (int*)alloc(MAXB * 4);
    int*   rstart = (int*)alloc((size_t)N * 4);
    int*   rend   = (int*)alloc((size_t)N * 4);
    float* dinv   = (float*)alloc((size_t)N * 4);
    int*   col    = (int*)alloc(((size_t)nbuck << CAPSH) * 4);   // ~12.8 MB
    size_t pair_b = ((size_t)nbuck << CAPSH) * 4;
    size_t hp_b   = (size_t)N * DH * 2;
    char*  bufA   = (char*)alloc(pair_b > hp_b ? pair_b : hp_b); // pairs / h1' alias (same spans!)
    u16*   bufB   = (u16*)alloc(hp_b);                           // h2' bf16
    u16*   hp    = (u16*)bufA;
    u32*   pairs = (u32*)bufA;

    int gN16 = (N + 15) / 16;

    hipMemsetAsync(gcnt, 0, (size_t)nbuck * 4, stream);
    binA_k<<<768, 256, 0, stream>>>(ei, gcnt, pairs, E, N, nbuck);
    // CSR build + layer-1 transform fused (pairs consumed, hp written in place)
    csr_gemm_k<<<nbuck, 512, 0, stream>>>(pairs, gcnt, rstart, rend, col, dinv, x, W1, N);
    // layer-1 aggregation fused with layer-2 transform: bufB = h2'
    agg_gemm_k<<<gN16, 256, 0, stream>>>(hp, rstart, rend, col, dinv, b1, W2, bufB, N);
    // layer-2 aggregation fused with head
    agg_head_k<<<gN16, 256, 0, stream>>>(bufB, rstart, rend, col, dinv, b2, Wo, bo, y, N);
}